// Round 1
// baseline (378.701 us; speedup 1.0000x reference)
//
#include <hip/hip_runtime.h>

typedef __bf16 bf16_t;
typedef __bf16 bf16x8 __attribute__((ext_vector_type(8)));
typedef float f32x4 __attribute__((ext_vector_type(4)));
typedef int   int4v __attribute__((ext_vector_type(4)));

#define LOG2E 1.4426950408889634f

template<int CTRL>
__device__ __forceinline__ float qperm(float x) {
  return __builtin_bit_cast(float,
      __builtin_amdgcn_update_dpp(0, __builtin_bit_cast(int, x), CTRL, 0xF, 0xF, true));
}

// LDS-only barrier: does NOT drain vmcnt, so global loads/stores stay in
// flight across steps (compiler's __syncthreads drains vmcnt(0) every step).
__device__ __forceinline__ void lds_barrier() {
  asm volatile("s_waitcnt lgkmcnt(0)\n\ts_barrier" ::: "memory");
}

// int8 dot4: D = c + sum_i a.b8[i]*b.b8[i]
#if __has_builtin(__builtin_amdgcn_sdot4)
__device__ __forceinline__ int DOT4(int a, int b, int c) {
  return __builtin_amdgcn_sdot4(a, b, c, false);
}
#else
// correctness fallback only (slow) — gfx950 has v_dot4_i32_i8
__device__ __forceinline__ int DOT4(int a, int b, int c) {
  #pragma unroll
  for (int i = 0; i < 4; ++i)
    c += ((a << (24 - 8 * i)) >> 24) * ((b << (24 - 8 * i)) >> 24);
  return c;
}
#endif

// ---------------------------------------------------------------------------
// K1: preT[dir][r][t] = (Wih_dir @ x[t_x]) + bih + bhh, gate-interleaved rows:
//     r = 4n + p  <->  original row j = 125*p + n   (n<125 valid, else 0)
//     t_x = t (fwd) or 511-t (bwd).
// MFMA GEMM with bf16 hi/lo split (Whi*xhi + Whi*xlo + Wlo*xhi): fp32-exact
// to ~2^-18.  grid = 64 blocks (dir*32 + row-tile T), 256 threads (4 waves),
// each wave does 8 t-tiles of 16.
// ---------------------------------------------------------------------------
__global__ __launch_bounds__(256) void pre_kernel(
    const float* __restrict__ x,     // [512][125]
    const float* __restrict__ Wih_f, const float* __restrict__ bih_f,
    const float* __restrict__ bhh_f,
    const float* __restrict__ Wih_b, const float* __restrict__ bih_b,
    const float* __restrict__ bhh_b,
    float* __restrict__ preT)        // [2][512 r][512 t]
{
  const int dir = blockIdx.x >> 5;
  const int T   = blockIdx.x & 31;
  const float* __restrict__ Wih = dir ? Wih_b : Wih_f;
  const float* __restrict__ bih = dir ? bih_b : bih_f;
  const float* __restrict__ bhh = dir ? bhh_b : bhh_f;

  const int tid = threadIdx.x;
  const int wv  = tid >> 6;
  const int lane = tid & 63;
  const int q = lane >> 4, cc = lane & 15;

  // A fragments for row-tile T: row r = 16T + cc, k = 32ks + 8q + j
  const int r  = 16 * T + cc;
  const int na = r >> 2, pa = r & 3;
  const bool vld = (na < 125);
  const float* __restrict__ Wr = Wih + (vld ? (125 * pa + na) * 125 : 0);

  bf16x8 whi[4], wlo[4];
  #pragma unroll
  for (int ks = 0; ks < 4; ++ks) {
    #pragma unroll
    for (int j = 0; j < 8; ++j) {
      int k = 32 * ks + 8 * q + j;
      float wvv = (vld && k < 125) ? Wr[k] : 0.0f;
      bf16_t hi = (bf16_t)wvv;
      whi[ks][j] = hi;
      wlo[ks][j] = (bf16_t)(wvv - (float)hi);
    }
  }

  // bias for the 4 output rows this lane stores
  float bias[4];
  #pragma unroll
  for (int reg = 0; reg < 4; ++reg) {
    int ro = 16 * T + 4 * q + reg;
    int no = ro >> 2, po = ro & 3;
    bias[reg] = (no < 125) ? (bih[125 * po + no] + bhh[125 * po + no]) : 0.0f;
  }

  for (int i = 0; i < 8; ++i) {
    const int tt = 8 * wv + i;
    const int t  = 16 * tt + cc;
    const int trow = dir ? (511 - t) : t;
    const float* __restrict__ xr = x + trow * 125;

    f32x4 acc = (f32x4)0.0f;
    #pragma unroll
    for (int ks = 0; ks < 4; ++ks) {
      bf16x8 xhi, xlo;
      #pragma unroll
      for (int j = 0; j < 8; ++j) {
        int k = 32 * ks + 8 * q + j;
        float xv = (k < 125) ? xr[k] : 0.0f;
        bf16_t hi = (bf16_t)xv;
        xhi[j] = hi;
        xlo[j] = (bf16_t)(xv - (float)hi);
      }
      acc = __builtin_amdgcn_mfma_f32_16x16x32_bf16(whi[ks], xhi, acc, 0, 0, 0);
      acc = __builtin_amdgcn_mfma_f32_16x16x32_bf16(whi[ks], xlo, acc, 0, 0, 0);
      acc = __builtin_amdgcn_mfma_f32_16x16x32_bf16(wlo[ks], xhi, acc, 0, 0, 0);
    }
    #pragma unroll
    for (int reg = 0; reg < 4; ++reg) {
      int ro = 16 * T + 4 * q + reg;
      preT[dir * 262144 + ro * 512 + 16 * tt + cc] = acc[reg] + bias[reg];
    }
  }
}

// ---------------------------------------------------------------------------
// K2: sequential LSTM.  grid = 2 blocks (dir), 512 threads (8 waves).
// Whh@h via v_dot4_i32_i8 (int8 quantized: h scale 127 exact since |h|<1;
// W global scale 127/max|W| computed on-device).  int32 accumulate is exact;
// dequant folded into the exp2 multiplier.  Thread tid owns gate p = tid&3
// of unit n = tid>>2 (row r = 4n+p = tid, matching pre's interleaved rows).
// h broadcast via 128-byte double-buffered LDS (uniform-address b128 reads
// are bank-conflict-free broadcasts).  No MFMA: the old path broadcast h
// across 16 B-columns, wasting 15/16 of the matrix pipe (~326 cy/step of
// matrix-pipe time per CU); dot4 does the same 62.5K MACs in 32 VALU
// insts/thread.
// ---------------------------------------------------------------------------
__global__ __launch_bounds__(512) void lstm_kernel(
    const float* __restrict__ Whh_f, const float* __restrict__ Whh_b,
    const float* __restrict__ pre,   // [2][512 r][512 t]
    bf16_t* __restrict__ h_all)      // [512][256]  (0:125 fwd | 125:250 bwd | 250:256 zero)
{
  const int dir = blockIdx.x;
  const float* __restrict__ Whh = dir ? Whh_b : Whh_f;

  const int tid  = threadIdx.x;
  const int lane = tid & 63;
  const int w    = tid >> 6;      // wave 0..7
  const int n    = tid >> 2;      // unit 0..127
  const int p    = tid & 3;       // gate index (i,f,g,o)
  const bool vld = (n < 125);
  const float* __restrict__ Wrow = Whh + (vld ? (125 * p + n) * 125 : 0);

  // ---- pass 1: global max |Whh| over used elements (4 chains to break dep) ----
  float m0 = 0.f, m1 = 0.f, m2 = 0.f, m3 = 0.f;
  if (vld) {
    #pragma unroll 4
    for (int k = 0; k < 124; k += 4) {
      m0 = fmaxf(m0, fabsf(Wrow[k + 0]));
      m1 = fmaxf(m1, fabsf(Wrow[k + 1]));
      m2 = fmaxf(m2, fabsf(Wrow[k + 2]));
      m3 = fmaxf(m3, fabsf(Wrow[k + 3]));
    }
    m0 = fmaxf(m0, fabsf(Wrow[124]));
  }
  float wm = fmaxf(fmaxf(m0, m1), fmaxf(m2, m3));
  #pragma unroll
  for (int off = 1; off < 64; off <<= 1)
    wm = fmaxf(wm, __shfl_xor(wm, off));
  __shared__ float wmx[8];
  if (lane == 0) wmx[w] = wm;
  __syncthreads();
  float wmax = wmx[0];
  #pragma unroll
  for (int u = 1; u < 8; ++u) wmax = fmaxf(wmax, wmx[u]);
  const float s_w  = 127.0f / wmax;
  const float invq = wmax / (127.0f * 127.0f);   // int D -> W@h

  // ---- pass 2: quantize own row into 32 packed-i8 dwords (k = 4*word+byte) ----
  int wq[32];
  #pragma unroll
  for (int word = 0; word < 32; ++word) {
    int b = 0;
    #pragma unroll
    for (int byte = 0; byte < 4; ++byte) {
      int k = 4 * word + byte;
      int qv = 0;
      if (vld && k < 125)
        qv = (int)__builtin_rintf(Wrow[k] * s_w);
      b |= (qv & 0xFF) << (8 * byte);
    }
    wq[word] = b;
  }

  __shared__ __align__(16) char hbuf[2][128];    // int8 h, double buffered
  if (tid < 256) ((char*)hbuf)[tid] = 0;
  // zero h_all pad columns once (dir 0 only)
  if (dir == 0) {
    #pragma unroll
    for (int u = 0; u < 6; ++u) h_all[tid * 256 + 250 + u] = (bf16_t)0.0f;
  }
  __syncthreads();

  const float mult   = (p == 2) ? (-2.0f * LOG2E) : (-LOG2E);
  const float sA     = (p == 2) ? 2.0f : 1.0f;
  const float sB     = (p == 2) ? -1.0f : 0.0f;
  const float dscale = mult * invq;              // int D -> exp2 argument
  const float* __restrict__ preR = pre + dir * 262144 + tid * 512;
  float c = 0.0f;

  float4 pv_cur = *(const float4*)preR;

  for (int g = 0; g < 128; ++g) {
    float4 pv_nxt = make_float4(0.f, 0.f, 0.f, 0.f);
    if (g < 127) pv_nxt = *(const float4*)(preR + 4 * (g + 1));

    #pragma unroll
    for (int s4 = 0; s4 < 4; ++s4) {
      const int step = 4 * g + s4;
      const int cur  = s4 & 1, nxt = cur ^ 1;
      const float pv = (s4 == 0) ? pv_cur.x : (s4 == 1) ? pv_cur.y
                     : (s4 == 2) ? pv_cur.z : pv_cur.w;
      const float pvm = mult * pv;               // off critical path

      // broadcast-read full h vector (32 dwords, uniform address)
      int hv[32];
      #pragma unroll
      for (int j = 0; j < 8; ++j) {
        int4v v = *(const int4v*)&hbuf[cur][16 * j];
        hv[4 * j + 0] = v[0];
        hv[4 * j + 1] = v[1];
        hv[4 * j + 2] = v[2];
        hv[4 * j + 3] = v[3];
      }

      // 125-long i8 dot, 4 parallel chains
      int d0 = 0, d1 = 0, d2 = 0, d3 = 0;
      #pragma unroll
      for (int j = 0; j < 8; ++j) {
        d0 = DOT4(wq[4 * j + 0], hv[4 * j + 0], d0);
        d1 = DOT4(wq[4 * j + 1], hv[4 * j + 1], d1);
        d2 = DOT4(wq[4 * j + 2], hv[4 * j + 2], d2);
        d3 = DOT4(wq[4 * j + 3], hv[4 * j + 3], d3);
      }
      const int D = (d0 + d1) + (d2 + d3);

      // uniform activation: y = sigmoid(scale*(W@h + pv)); act = sA*y + sB
      float gf  = (float)D;
      float xg  = fmaf(gf, dscale, pvm);
      float e   = __builtin_amdgcn_exp2f(xg);
      float y   = __builtin_amdgcn_rcpf(1.0f + e);
      float act = fmaf(y, sA, sB);

      // quad: p0=i, p1=f, p2=g~, p3=o  (flat broadcast tree)
      float b_i = qperm<0x00>(act);
      float b_f = qperm<0x55>(act);
      float b_g = qperm<0xAA>(act);
      float b_o = qperm<0xFF>(act);
      c = fmaf(b_f, c, b_i * b_g);               // c = f*c + i*g~
      float e2 = __builtin_amdgcn_exp2f(-2.0f * LOG2E * c);
      float tc = fmaf(__builtin_amdgcn_rcpf(1.0f + e2), 2.0f, -1.0f);
      float h  = b_o * tc;

      if (p == 0) {
        int qh = (int)__builtin_rintf(h * 127.0f);
        hbuf[nxt][n] = (char)qh;                 // pad units harmless (wq=0 there)
        if (n < 125) {
          int t_orig = dir ? (511 - step) : step;
          h_all[t_orig * 256 + dir * 125 + n] = (bf16_t)h;
        }
      }
      lds_barrier();
    }
    pv_cur = pv_nxt;
  }
}

// ---------------------------------------------------------------------------
// K3: Qa[j][m] = C2 * (h @ W1[:, :250].T),  Qb[j][m] = C2 * (h @ W1[:, 250:].T + b1)
//     C2 = 2*log2(e) folded in for K4's exp2.  bf16 MFMA, one 16x16 tile/wave.
// ---------------------------------------------------------------------------
__global__ __launch_bounds__(256) void qgemm_kernel(
    const bf16_t* __restrict__ h_all, // [512][256]
    const float* __restrict__ W1,     // [512][500]
    const float* __restrict__ b1,     // [512]
    float* __restrict__ Qa,           // [512][512]
    float* __restrict__ Qb)           // [512][512]
{
  const int tid  = threadIdx.x;
  const int wv   = tid >> 6;
  const int lane = tid & 63;
  const int q    = lane >> 4, cc = lane & 15;
  const int bj   = blockIdx.x & 31;    // j tile
  const int bm   = blockIdx.x >> 5;    // m group
  const int m    = bm * 64 + wv * 16 + cc;   // [0,1024)
  const int j0   = bj * 16;
  const int jA   = j0 + cc;

  const bool isB = (m >= 512);
  const int  row = isB ? (m - 512) : m;
  const int  cof = isB ? 250 : 0;

  f32x4 acc = (f32x4)0.0f;
  #pragma unroll
  for (int ks = 0; ks < 8; ++ks) {
    int kb = 32 * ks + 8 * q;
    bf16x8 a = *(const bf16x8*)&h_all[jA * 256 + kb];
    bf16x8 b;
    #pragma unroll
    for (int jj = 0; jj < 8; ++jj) {
      int k = kb + jj;
      float v = (k < 250) ? W1[row * 500 + cof + k] : 0.0f;
      b[jj] = (bf16_t)v;
    }
    acc = __builtin_amdgcn_mfma_f32_16x16x32_bf16(a, b, acc, 0, 0, 0);
  }

  const float C2 = 2.0f * LOG2E;
  #pragma unroll
  for (int reg = 0; reg < 4; ++reg) {
    int j = j0 + 4 * q + reg;
    float v = acc[reg];
    if (!isB) Qa[j * 512 + m] = C2 * v;
    else      Qb[j * 512 + (m - 512)] = C2 * (v + b1[m - 512]);
  }
}

// ---------------------------------------------------------------------------
// K4: out[i][j] = b2 + sum_k W2[k] * tanh(...)
//     tanh = 1 - 2*rcp(1 + exp2(sa[j,k] + sb[i,k]))   (C2 pre-folded)
//     accumulate accR = sum w*r;  out = wsum - 2*accR + b2
// ---------------------------------------------------------------------------
__global__ __launch_bounds__(256) void outer_kernel(
    const float* __restrict__ Qa, const float* __restrict__ Qb,
    const float* __restrict__ W2, const float* __restrict__ b2,
    float* __restrict__ out)
{
  __shared__ float sa[2][32][33];
  __shared__ float sb[2][32][33];
  __shared__ float sw[2][32];

  const int tid = threadIdx.x;
  const int bi  = blockIdx.x >> 4, bjx = blockIdx.x & 15;
  const int i0  = bi * 32, j0 = bjx * 32;
  const int ii0 = (tid & 15) * 2;
  const int jj0 = (tid >> 4) * 2;
  const int ljj = tid & 31, kk4 = (tid >> 5) * 4;

  float accR[2][2] = {{0.0f, 0.0f}, {0.0f, 0.0f}};
  float wsum = 0.0f;

  for (int kc = 0; kc < 16; ++kc) {
    const int buf = kc & 1;
    const int k0  = kc * 32;
    float4 va = *(const float4*)&Qa[(j0 + ljj) * 512 + k0 + kk4];
    float4 vb = *(const float4*)&Qb[(i0 + ljj) * 512 + k0 + kk4];
    sa[buf][kk4 + 0][ljj] = va.x; sa[buf][kk4 + 1][ljj] = va.y;
    sa[buf][kk4 + 2][ljj] = va.z; sa[buf][kk4 + 3][ljj] = va.w;
    sb[buf][kk4 + 0][ljj] = vb.x; sb[buf][kk4 + 1][ljj] = vb.y;
    sb[buf][kk4 + 2][ljj] = vb.z; sb[buf][kk4 + 3][ljj] = vb.w;
    if (tid < 32) sw[buf][tid] = W2[k0 + tid];
    __syncthreads();

    #pragma unroll 4
    for (int kk = 0; kk < 32; ++kk) {
      float2 av = *(const float2*)&sa[buf][kk][jj0];
      float2 bv = *(const float2*)&sb[buf][kk][ii0];
      float wk = sw[buf][kk];
      wsum += wk;
      {
        float e = __builtin_amdgcn_exp2f(av.x + bv.x);
        accR[0][0] = fmaf(wk, __builtin_amdgcn_rcpf(1.0f + e), accR[0][0]);
      }
      {
        float e = __builtin_amdgcn_exp2f(av.y + bv.x);
        accR[0][1] = fmaf(wk, __builtin_amdgcn_rcpf(1.0f + e), accR[0][1]);
      }
      {
        float e = __builtin_amdgcn_exp2f(av.x + bv.y);
        accR[1][0] = fmaf(wk, __builtin_amdgcn_rcpf(1.0f + e), accR[1][0]);
      }
      {
        float e = __builtin_amdgcn_exp2f(av.y + bv.y);
        accR[1][1] = fmaf(wk, __builtin_amdgcn_rcpf(1.0f + e), accR[1][1]);
      }
    }
  }

  const float bb = b2[0];
  #pragma unroll
  for (int i2 = 0; i2 < 2; ++i2)
    #pragma unroll
    for (int j2 = 0; j2 < 2; ++j2)
      out[(i0 + ii0 + i2) * 512 + (j0 + jj0 + j2)] =
          wsum - 2.0f * accR[i2][j2] + bb;
}

// ---------------------------------------------------------------------------
extern "C" void kernel_launch(void* const* d_in, const int* in_sizes, int n_in,
                              void* d_out, int out_size, void* d_ws, size_t ws_size,
                              hipStream_t stream) {
  const float* emb   = (const float*)d_in[0];
  const float* Wih_f = (const float*)d_in[1];
  const float* Whh_f = (const float*)d_in[2];
  const float* bih_f = (const float*)d_in[3];
  const float* bhh_f = (const float*)d_in[4];
  const float* Wih_b = (const float*)d_in[5];
  const float* Whh_b = (const float*)d_in[6];
  const float* bih_b = (const float*)d_in[7];
  const float* bhh_b = (const float*)d_in[8];
  const float* W1    = (const float*)d_in[9];
  const float* b1    = (const float*)d_in[10];
  const float* W2    = (const float*)d_in[11];
  const float* b2    = (const float*)d_in[12];
  float* out = (float*)d_out;

  char* ws = (char*)d_ws;
  float*  pre   = (float*)ws;                                  // 2 MB
  bf16_t* h_all = (bf16_t*)(ws + 2 * 1024 * 1024);             // 256 KB
  float*  Qa    = (float*)(ws + 2 * 1024 * 1024 + 256 * 1024); // 1 MB
  float*  Qb    = Qa + 512 * 512;                              // 1 MB

  pre_kernel<<<64, 256, 0, stream>>>(emb, Wih_f, bih_f, bhh_f,
                                     Wih_b, bih_b, bhh_b, pre);
  lstm_kernel<<<2, 512, 0, stream>>>(Whh_f, Whh_b, pre, h_all);
  qgemm_kernel<<<512, 256, 0, stream>>>(h_all, W1, b1, Qa, Qb);
  outer_kernel<<<256, 256, 0, stream>>>(Qa, Qb, W2, b2, out);
}

// Round 2
// 371.770 us; speedup vs baseline: 1.0186x; 1.0186x over previous
//
#include <hip/hip_runtime.h>

typedef __bf16 bf16_t;
typedef __bf16 bf16x8 __attribute__((ext_vector_type(8)));
typedef float f32x4 __attribute__((ext_vector_type(4)));
typedef int   int4v __attribute__((ext_vector_type(4)));

#define LOG2E 1.4426950408889634f

template<int CTRL>
__device__ __forceinline__ float qperm(float x) {
  return __builtin_bit_cast(float,
      __builtin_amdgcn_update_dpp(0, __builtin_bit_cast(int, x), CTRL, 0xF, 0xF, true));
}

template<int CTRL>
__device__ __forceinline__ int iperm(int x) {
  return __builtin_amdgcn_update_dpp(0, x, CTRL, 0xF, 0xF, true);
}

// LDS-only barrier: does NOT drain vmcnt, so global loads/stores stay in
// flight across steps (compiler's __syncthreads drains vmcnt(0) every step).
__device__ __forceinline__ void lds_barrier() {
  asm volatile("s_waitcnt lgkmcnt(0)\n\ts_barrier" ::: "memory");
}

// int8 dot4: D = c + sum_i a.b8[i]*b.b8[i]
#if __has_builtin(__builtin_amdgcn_sdot4)
__device__ __forceinline__ int DOT4(int a, int b, int c) {
  return __builtin_amdgcn_sdot4(a, b, c, false);
}
#else
// correctness fallback only (slow)
__device__ __forceinline__ int DOT4(int a, int b, int c) {
  #pragma unroll
  for (int i = 0; i < 4; ++i)
    c += ((a << (24 - 8 * i)) >> 24) * ((b << (24 - 8 * i)) >> 24);
  return c;
}
#endif

// ---------------------------------------------------------------------------
// K1: preT[dir][r][t] = (Wih_dir @ x[t_x]) + bih + bhh, gate-interleaved rows:
//     r = 4n + p  <->  original row j = 125*p + n   (n<125 valid, else 0)
//     t_x = t (fwd) or 511-t (bwd).
// MFMA GEMM with bf16 hi/lo split (Whi*xhi + Whi*xlo + Wlo*xhi): fp32-exact
// to ~2^-18.  grid = 64 blocks (dir*32 + row-tile T), 256 threads (4 waves),
// each wave does 8 t-tiles of 16.
// ---------------------------------------------------------------------------
__global__ __launch_bounds__(256) void pre_kernel(
    const float* __restrict__ x,     // [512][125]
    const float* __restrict__ Wih_f, const float* __restrict__ bih_f,
    const float* __restrict__ bhh_f,
    const float* __restrict__ Wih_b, const float* __restrict__ bih_b,
    const float* __restrict__ bhh_b,
    float* __restrict__ preT)        // [2][512 r][512 t]
{
  const int dir = blockIdx.x >> 5;
  const int T   = blockIdx.x & 31;
  const float* __restrict__ Wih = dir ? Wih_b : Wih_f;
  const float* __restrict__ bih = dir ? bih_b : bih_f;
  const float* __restrict__ bhh = dir ? bhh_b : bhh_f;

  const int tid = threadIdx.x;
  const int wv  = tid >> 6;
  const int lane = tid & 63;
  const int q = lane >> 4, cc = lane & 15;

  // A fragments for row-tile T: row r = 16T + cc, k = 32ks + 8q + j
  const int r  = 16 * T + cc;
  const int na = r >> 2, pa = r & 3;
  const bool vld = (na < 125);
  const float* __restrict__ Wr = Wih + (vld ? (125 * pa + na) * 125 : 0);

  bf16x8 whi[4], wlo[4];
  #pragma unroll
  for (int ks = 0; ks < 4; ++ks) {
    #pragma unroll
    for (int j = 0; j < 8; ++j) {
      int k = 32 * ks + 8 * q + j;
      float wvv = (vld && k < 125) ? Wr[k] : 0.0f;
      bf16_t hi = (bf16_t)wvv;
      whi[ks][j] = hi;
      wlo[ks][j] = (bf16_t)(wvv - (float)hi);
    }
  }

  // bias for the 4 output rows this lane stores
  float bias[4];
  #pragma unroll
  for (int reg = 0; reg < 4; ++reg) {
    int ro = 16 * T + 4 * q + reg;
    int no = ro >> 2, po = ro & 3;
    bias[reg] = (no < 125) ? (bih[125 * po + no] + bhh[125 * po + no]) : 0.0f;
  }

  for (int i = 0; i < 8; ++i) {
    const int tt = 8 * wv + i;
    const int t  = 16 * tt + cc;
    const int trow = dir ? (511 - t) : t;
    const float* __restrict__ xr = x + trow * 125;

    f32x4 acc = (f32x4)0.0f;
    #pragma unroll
    for (int ks = 0; ks < 4; ++ks) {
      bf16x8 xhi, xlo;
      #pragma unroll
      for (int j = 0; j < 8; ++j) {
        int k = 32 * ks + 8 * q + j;
        float xv = (k < 125) ? xr[k] : 0.0f;
        bf16_t hi = (bf16_t)xv;
        xhi[j] = hi;
        xlo[j] = (bf16_t)(xv - (float)hi);
      }
      acc = __builtin_amdgcn_mfma_f32_16x16x32_bf16(whi[ks], xhi, acc, 0, 0, 0);
      acc = __builtin_amdgcn_mfma_f32_16x16x32_bf16(whi[ks], xlo, acc, 0, 0, 0);
      acc = __builtin_amdgcn_mfma_f32_16x16x32_bf16(wlo[ks], xhi, acc, 0, 0, 0);
    }
    #pragma unroll
    for (int reg = 0; reg < 4; ++reg) {
      int ro = 16 * T + 4 * q + reg;
      preT[dir * 262144 + ro * 512 + 16 * tt + cc] = acc[reg] + bias[reg];
    }
  }
}

// ---------------------------------------------------------------------------
// K2: sequential LSTM.  grid = 2 blocks (dir), 512 threads (8 waves).
// Whh@h via v_dot4_i32_i8, K-SPLIT ACROSS EACH QUAD:
//   thread (n, p) loads only k-quarter p of h (32 B = 2 x ds_read_b128,
//   16 b128/step/CU vs 64 in the all-k variant -- the LDS return bus
//   delivers 16 B to all 64 lanes per b128, so broadcast reads still cost
//   full return bandwidth) and computes partial dots for ALL 4 gates of
//   unit n over that quarter (32 dot4, same as before).  A 4x4 in-quad
//   DPP transpose-reduce (2 butterfly stages, compile-time reg selects)
//   lands the full dot for gate p on lane p.  int32 accumulate exact.
// ---------------------------------------------------------------------------
__global__ __launch_bounds__(512) void lstm_kernel(
    const float* __restrict__ Whh_f, const float* __restrict__ Whh_b,
    const float* __restrict__ pre,   // [2][512 r][512 t]
    bf16_t* __restrict__ h_all)      // [512][256]  (0:125 fwd | 125:250 bwd | 250:256 zero)
{
  const int dir = blockIdx.x;
  const float* __restrict__ Whh = dir ? Whh_b : Whh_f;

  const int tid  = threadIdx.x;
  const int lane = tid & 63;
  const int w    = tid >> 6;      // wave 0..7
  const int n    = tid >> 2;      // unit 0..127
  const int p    = tid & 3;       // gate index (i,f,g,o) AND k-quarter
  const bool vld = (n < 125);
  const int  klim = (p == 3) ? 29 : 32;   // valid k in this quarter

  // ---- pass 1: global max |Whh| over used elements ----
  float m0 = 0.f, m1 = 0.f, m2 = 0.f, m3 = 0.f;
  if (vld) {
    #pragma unroll
    for (int g4 = 0; g4 < 4; ++g4) {
      const float* __restrict__ Wg = Whh + (125 * g4 + n) * 125 + 32 * p;
      for (int j = 0; j + 3 < klim; j += 4) {
        m0 = fmaxf(m0, fabsf(Wg[j + 0]));
        m1 = fmaxf(m1, fabsf(Wg[j + 1]));
        m2 = fmaxf(m2, fabsf(Wg[j + 2]));
        m3 = fmaxf(m3, fabsf(Wg[j + 3]));
      }
      if (klim == 29) m0 = fmaxf(m0, fabsf(Wg[28]));
    }
  }
  float wm = fmaxf(fmaxf(m0, m1), fmaxf(m2, m3));
  #pragma unroll
  for (int off = 1; off < 64; off <<= 1)
    wm = fmaxf(wm, __shfl_xor(wm, off));
  __shared__ float wmx[8];
  if (lane == 0) wmx[w] = wm;
  __syncthreads();
  float wmax = wmx[0];
  #pragma unroll
  for (int u = 1; u < 8; ++u) wmax = fmaxf(wmax, wmx[u]);
  const float s_w  = 127.0f / wmax;
  const float invq = wmax / (127.0f * 127.0f);   // int D -> W@h

  // ---- pass 2: quantize 4 gate-rows x own k-quarter into 32 packed dwords ----
  int wq[4][8];
  #pragma unroll
  for (int g4 = 0; g4 < 4; ++g4) {
    const float* __restrict__ Wg = Whh + (vld ? (125 * g4 + n) * 125 : 0);
    #pragma unroll
    for (int word = 0; word < 8; ++word) {
      int b = 0;
      #pragma unroll
      for (int byte = 0; byte < 4; ++byte) {
        int k = 32 * p + 4 * word + byte;
        int qv = 0;
        if (vld && k < 125)
          qv = (int)__builtin_rintf(Wg[k] * s_w);
        b |= (qv & 0xFF) << (8 * byte);
      }
      wq[g4][word] = b;
    }
  }

  __shared__ __align__(16) char hbuf[2][128];    // int8 h, double buffered
  if (tid < 256) ((char*)hbuf)[tid] = 0;
  // zero h_all pad columns once (dir 0 only)
  if (dir == 0) {
    #pragma unroll
    for (int u = 0; u < 6; ++u) h_all[tid * 256 + 250 + u] = (bf16_t)0.0f;
  }
  __syncthreads();

  const float mult   = (p == 2) ? (-2.0f * LOG2E) : (-LOG2E);
  const float sA     = (p == 2) ? 2.0f : 1.0f;
  const float sB     = (p == 2) ? -1.0f : 0.0f;
  const float dscale = mult * invq;              // int D -> exp2 argument
  const int   q0 = p & 1, q1 = p >> 1;
  const float* __restrict__ preR = pre + dir * 262144 + tid * 512;
  float c = 0.0f;

  float4 pv_cur = *(const float4*)preR;

  for (int g = 0; g < 128; ++g) {
    float4 pv_nxt = make_float4(0.f, 0.f, 0.f, 0.f);
    if (g < 127) pv_nxt = *(const float4*)(preR + 4 * (g + 1));

    #pragma unroll
    for (int s4 = 0; s4 < 4; ++s4) {
      const int step = 4 * g + s4;
      const int cur  = s4 & 1, nxt = cur ^ 1;
      const float pv = (s4 == 0) ? pv_cur.x : (s4 == 1) ? pv_cur.y
                     : (s4 == 2) ? pv_cur.z : pv_cur.w;
      const float pvm = mult * pv;               // off critical path

      // own k-quarter of h (32 B): 2 x b128, broadcast to 16 lanes each
      int4v h0 = *(const int4v*)&hbuf[cur][32 * p];
      int4v h1 = *(const int4v*)&hbuf[cur][32 * p + 16];

      // partial dots for all 4 gates of unit n over this quarter
      int d0 = 0, d1 = 0, d2 = 0, d3 = 0;
      #pragma unroll
      for (int j = 0; j < 4; ++j) {
        d0 = DOT4(wq[0][j], h0[j], d0);
        d1 = DOT4(wq[1][j], h0[j], d1);
        d2 = DOT4(wq[2][j], h0[j], d2);
        d3 = DOT4(wq[3][j], h0[j], d3);
      }
      #pragma unroll
      for (int j = 0; j < 4; ++j) {
        d0 = DOT4(wq[0][4 + j], h1[j], d0);
        d1 = DOT4(wq[1][4 + j], h1[j], d1);
        d2 = DOT4(wq[2][4 + j], h1[j], d2);
        d3 = DOT4(wq[3][4 + j], h1[j], d3);
      }

      // 4x4 in-quad transpose-reduce: lane p ends with full dot of gate p.
      // Stage 1 (xor bit0, quad_perm [1,0,3,2] = 0xB1):
      int x0 = q0 ? d1 : d0;       // own partial, gate {g1=0, g0=q0}
      int x1 = q0 ? d3 : d2;       // own partial, gate {g1=1, g0=q0}
      int y0 = q0 ? d0 : d1;       // partner's wanted gate {g1=0, g0=!q0}
      int y1 = q0 ? d2 : d3;
      int a0 = x0 + iperm<0xB1>(y0);
      int a1 = x1 + iperm<0xB1>(y1);
      // Stage 2 (xor bit1, quad_perm [2,3,0,1] = 0x4E):
      int xx = q1 ? a1 : a0;
      int yy = q1 ? a0 : a1;
      const int D = xx + iperm<0x4E>(yy);

      // uniform activation: y = sigmoid(scale*(W@h + pv)); act = sA*y + sB
      float gf  = (float)D;
      float xg  = fmaf(gf, dscale, pvm);
      float e   = __builtin_amdgcn_exp2f(xg);
      float y   = __builtin_amdgcn_rcpf(1.0f + e);
      float act = fmaf(y, sA, sB);

      // quad: p0=i, p1=f, p2=g~, p3=o  (flat broadcast tree)
      float b_i = qperm<0x00>(act);
      float b_f = qperm<0x55>(act);
      float b_g = qperm<0xAA>(act);
      float b_o = qperm<0xFF>(act);
      c = fmaf(b_f, c, b_i * b_g);               // c = f*c + i*g~
      float e2 = __builtin_amdgcn_exp2f(-2.0f * LOG2E * c);
      float tc = fmaf(__builtin_amdgcn_rcpf(1.0f + e2), 2.0f, -1.0f);
      float h  = b_o * tc;

      if (p == 0) {
        int qh = (int)__builtin_rintf(h * 127.0f);
        hbuf[nxt][n] = (char)qh;                 // pad units stay exactly 0
        if (n < 125) {
          int t_orig = dir ? (511 - step) : step;
          h_all[t_orig * 256 + dir * 125 + n] = (bf16_t)h;
        }
      }
      lds_barrier();
    }
    pv_cur = pv_nxt;
  }
}

// ---------------------------------------------------------------------------
// K3: Qa[j][m] = C2 * (h @ W1[:, :250].T),  Qb[j][m] = C2 * (h @ W1[:, 250:].T + b1)
//     C2 = 2*log2(e) folded in for K4's exp2.  bf16 MFMA, one 16x16 tile/wave.
// ---------------------------------------------------------------------------
__global__ __launch_bounds__(256) void qgemm_kernel(
    const bf16_t* __restrict__ h_all, // [512][256]
    const float* __restrict__ W1,     // [512][500]
    const float* __restrict__ b1,     // [512]
    float* __restrict__ Qa,           // [512][512]
    float* __restrict__ Qb)           // [512][512]
{
  const int tid  = threadIdx.x;
  const int wv   = tid >> 6;
  const int lane = tid & 63;
  const int q    = lane >> 4, cc = lane & 15;
  const int bj   = blockIdx.x & 31;    // j tile
  const int bm   = blockIdx.x >> 5;    // m group
  const int m    = bm * 64 + wv * 16 + cc;   // [0,1024)
  const int j0   = bj * 16;
  const int jA   = j0 + cc;

  const bool isB = (m >= 512);
  const int  row = isB ? (m - 512) : m;
  const int  cof = isB ? 250 : 0;

  f32x4 acc = (f32x4)0.0f;
  #pragma unroll
  for (int ks = 0; ks < 8; ++ks) {
    int kb = 32 * ks + 8 * q;
    bf16x8 a = *(const bf16x8*)&h_all[jA * 256 + kb];
    bf16x8 b;
    #pragma unroll
    for (int jj = 0; jj < 8; ++jj) {
      int k = kb + jj;
      float v = (k < 250) ? W1[row * 500 + cof + k] : 0.0f;
      b[jj] = (bf16_t)v;
    }
    acc = __builtin_amdgcn_mfma_f32_16x16x32_bf16(a, b, acc, 0, 0, 0);
  }

  const float C2 = 2.0f * LOG2E;
  #pragma unroll
  for (int reg = 0; reg < 4; ++reg) {
    int j = j0 + 4 * q + reg;
    float v = acc[reg];
    if (!isB) Qa[j * 512 + m] = C2 * v;
    else      Qb[j * 512 + (m - 512)] = C2 * (v + b1[m - 512]);
  }
}

// ---------------------------------------------------------------------------
// K4: out[i][j] = b2 + sum_k W2[k] * tanh(...)
//     tanh = 1 - 2*rcp(1 + exp2(sa[j,k] + sb[i,k]))   (C2 pre-folded)
//     accumulate accR = sum w*r;  out = wsum - 2*accR + b2
// ---------------------------------------------------------------------------
__global__ __launch_bounds__(256) void outer_kernel(
    const float* __restrict__ Qa, const float* __restrict__ Qb,
    const float* __restrict__ W2, const float* __restrict__ b2,
    float* __restrict__ out)
{
  __shared__ float sa[2][32][33];
  __shared__ float sb[2][32][33];
  __shared__ float sw[2][32];

  const int tid = threadIdx.x;
  const int bi  = blockIdx.x >> 4, bjx = blockIdx.x & 15;
  const int i0  = bi * 32, j0 = bjx * 32;
  const int ii0 = (tid & 15) * 2;
  const int jj0 = (tid >> 4) * 2;
  const int ljj = tid & 31, kk4 = (tid >> 5) * 4;

  float accR[2][2] = {{0.0f, 0.0f}, {0.0f, 0.0f}};
  float wsum = 0.0f;

  for (int kc = 0; kc < 16; ++kc) {
    const int buf = kc & 1;
    const int k0  = kc * 32;
    float4 va = *(const float4*)&Qa[(j0 + ljj) * 512 + k0 + kk4];
    float4 vb = *(const float4*)&Qb[(i0 + ljj) * 512 + k0 + kk4];
    sa[buf][kk4 + 0][ljj] = va.x; sa[buf][kk4 + 1][ljj] = va.y;
    sa[buf][kk4 + 2][ljj] = va.z; sa[buf][kk4 + 3][ljj] = va.w;
    sb[buf][kk4 + 0][ljj] = vb.x; sb[buf][kk4 + 1][ljj] = vb.y;
    sb[buf][kk4 + 2][ljj] = vb.z; sb[buf][kk4 + 3][ljj] = vb.w;
    if (tid < 32) sw[buf][tid] = W2[k0 + tid];
    __syncthreads();

    #pragma unroll 4
    for (int kk = 0; kk < 32; ++kk) {
      float2 av = *(const float2*)&sa[buf][kk][jj0];
      float2 bv = *(const float2*)&sb[buf][kk][ii0];
      float wk = sw[buf][kk];
      wsum += wk;
      {
        float e = __builtin_amdgcn_exp2f(av.x + bv.x);
        accR[0][0] = fmaf(wk, __builtin_amdgcn_rcpf(1.0f + e), accR[0][0]);
      }
      {
        float e = __builtin_amdgcn_exp2f(av.y + bv.x);
        accR[0][1] = fmaf(wk, __builtin_amdgcn_rcpf(1.0f + e), accR[0][1]);
      }
      {
        float e = __builtin_amdgcn_exp2f(av.x + bv.y);
        accR[1][0] = fmaf(wk, __builtin_amdgcn_rcpf(1.0f + e), accR[1][0]);
      }
      {
        float e = __builtin_amdgcn_exp2f(av.y + bv.y);
        accR[1][1] = fmaf(wk, __builtin_amdgcn_rcpf(1.0f + e), accR[1][1]);
      }
    }
  }

  const float bb = b2[0];
  #pragma unroll
  for (int i2 = 0; i2 < 2; ++i2)
    #pragma unroll
    for (int j2 = 0; j2 < 2; ++j2)
      out[(i0 + ii0 + i2) * 512 + (j0 + jj0 + j2)] =
          wsum - 2.0f * accR[i2][j2] + bb;
}

// ---------------------------------------------------------------------------
extern "C" void kernel_launch(void* const* d_in, const int* in_sizes, int n_in,
                              void* d_out, int out_size, void* d_ws, size_t ws_size,
                              hipStream_t stream) {
  const float* emb   = (const float*)d_in[0];
  const float* Wih_f = (const float*)d_in[1];
  const float* Whh_f = (const float*)d_in[2];
  const float* bih_f = (const float*)d_in[3];
  const float* bhh_f = (const float*)d_in[4];
  const float* Wih_b = (const float*)d_in[5];
  const float* Whh_b = (const float*)d_in[6];
  const float* bih_b = (const float*)d_in[7];
  const float* bhh_b = (const float*)d_in[8];
  const float* W1    = (const float*)d_in[9];
  const float* b1    = (const float*)d_in[10];
  const float* W2    = (const float*)d_in[11];
  const float* b2    = (const float*)d_in[12];
  float* out = (float*)d_out;

  char* ws = (char*)d_ws;
  float*  pre   = (float*)ws;                                  // 2 MB
  bf16_t* h_all = (bf16_t*)(ws + 2 * 1024 * 1024);             // 256 KB
  float*  Qa    = (float*)(ws + 2 * 1024 * 1024 + 256 * 1024); // 1 MB
  float*  Qb    = Qa + 512 * 512;                              // 1 MB

  pre_kernel<<<64, 256, 0, stream>>>(emb, Wih_f, bih_f, bhh_f,
                                     Wih_b, bih_b, bhh_b, pre);
  lstm_kernel<<<2, 512, 0, stream>>>(Whh_f, Whh_b, pre, h_all);
  qgemm_kernel<<<512, 256, 0, stream>>>(h_all, W1, b1, Qa, Qb);
  outer_kernel<<<256, 256, 0, stream>>>(Qa, Qb, W2, b2, out);
}

// Round 3
// 324.768 us; speedup vs baseline: 1.1661x; 1.1447x over previous
//
#include <hip/hip_runtime.h>

typedef __bf16 bf16_t;
typedef __bf16 bf16x8 __attribute__((ext_vector_type(8)));
typedef float f32x4 __attribute__((ext_vector_type(4)));
typedef int   int4v __attribute__((ext_vector_type(4)));

#define LOG2E 1.4426950408889634f

template<int CTRL>
__device__ __forceinline__ float qperm(float x) {
  return __builtin_bit_cast(float,
      __builtin_amdgcn_update_dpp(0, __builtin_bit_cast(int, x), CTRL, 0xF, 0xF, true));
}

// LDS-only barrier: does NOT drain vmcnt, so global loads/stores stay in
// flight across steps (compiler's __syncthreads drains vmcnt(0) every step).
__device__ __forceinline__ void lds_barrier() {
  asm volatile("s_waitcnt lgkmcnt(0)\n\ts_barrier" ::: "memory");
}

// ---------------------------------------------------------------------------
// K1: preT[dir][r][t] = (Wih_dir @ x[t_x]) + bih + bhh, gate-interleaved rows:
//     r = 4n + p  <->  original row j = 125*p + n   (n<125 valid, else 0)
//     t_x = t (fwd) or 511-t (bwd).
// MFMA GEMM with bf16 hi/lo split (Whi*xhi + Whi*xlo + Wlo*xhi): fp32-exact
// to ~2^-18.  grid = 64 blocks (dir*32 + row-tile T), 256 threads (4 waves),
// each wave does 8 t-tiles of 16.
// ---------------------------------------------------------------------------
__global__ __launch_bounds__(256) void pre_kernel(
    const float* __restrict__ x,     // [512][125]
    const float* __restrict__ Wih_f, const float* __restrict__ bih_f,
    const float* __restrict__ bhh_f,
    const float* __restrict__ Wih_b, const float* __restrict__ bih_b,
    const float* __restrict__ bhh_b,
    float* __restrict__ preT)        // [2][512 r][512 t]
{
  const int dir = blockIdx.x >> 5;
  const int T   = blockIdx.x & 31;
  const float* __restrict__ Wih = dir ? Wih_b : Wih_f;
  const float* __restrict__ bih = dir ? bih_b : bih_f;
  const float* __restrict__ bhh = dir ? bhh_b : bhh_f;

  const int tid = threadIdx.x;
  const int wv  = tid >> 6;
  const int lane = tid & 63;
  const int q = lane >> 4, cc = lane & 15;

  // A fragments for row-tile T: row r = 16T + cc, k = 32ks + 8q + j
  const int r  = 16 * T + cc;
  const int na = r >> 2, pa = r & 3;
  const bool vld = (na < 125);
  const float* __restrict__ Wr = Wih + (vld ? (125 * pa + na) * 125 : 0);

  bf16x8 whi[4], wlo[4];
  #pragma unroll
  for (int ks = 0; ks < 4; ++ks) {
    #pragma unroll
    for (int j = 0; j < 8; ++j) {
      int k = 32 * ks + 8 * q + j;
      float wvv = (vld && k < 125) ? Wr[k] : 0.0f;
      bf16_t hi = (bf16_t)wvv;
      whi[ks][j] = hi;
      wlo[ks][j] = (bf16_t)(wvv - (float)hi);
    }
  }

  // bias for the 4 output rows this lane stores
  float bias[4];
  #pragma unroll
  for (int reg = 0; reg < 4; ++reg) {
    int ro = 16 * T + 4 * q + reg;
    int no = ro >> 2, po = ro & 3;
    bias[reg] = (no < 125) ? (bih[125 * po + no] + bhh[125 * po + no]) : 0.0f;
  }

  for (int i = 0; i < 8; ++i) {
    const int tt = 8 * wv + i;
    const int t  = 16 * tt + cc;
    const int trow = dir ? (511 - t) : t;
    const float* __restrict__ xr = x + trow * 125;

    f32x4 acc = (f32x4)0.0f;
    #pragma unroll
    for (int ks = 0; ks < 4; ++ks) {
      bf16x8 xhi, xlo;
      #pragma unroll
      for (int j = 0; j < 8; ++j) {
        int k = 32 * ks + 8 * q + j;
        float xv = (k < 125) ? xr[k] : 0.0f;
        bf16_t hi = (bf16_t)xv;
        xhi[j] = hi;
        xlo[j] = (bf16_t)(xv - (float)hi);
      }
      acc = __builtin_amdgcn_mfma_f32_16x16x32_bf16(whi[ks], xhi, acc, 0, 0, 0);
      acc = __builtin_amdgcn_mfma_f32_16x16x32_bf16(whi[ks], xlo, acc, 0, 0, 0);
      acc = __builtin_amdgcn_mfma_f32_16x16x32_bf16(wlo[ks], xhi, acc, 0, 0, 0);
    }
    #pragma unroll
    for (int reg = 0; reg < 4; ++reg) {
      int ro = 16 * T + 4 * q + reg;
      preT[dir * 262144 + ro * 512 + 16 * tt + cc] = acc[reg] + bias[reg];
    }
  }
}

// ---------------------------------------------------------------------------
// K2: sequential LSTM.  grid = 2 blocks (dir), 512 threads (8 waves).
// Whh@h via mfma_i32_16x16x64_i8 (int8 quantized: h scale 127 exact since
// |h|<1; W global scale 127/max|W| computed on-device).  int32 accumulate is
// exact; dequant folded into the exp2 multiplier.
// Lane 16q + 4lt + p owns gate p of unit n = 16w + 4lt + q.
// (Round-0 proven structure: MFMA keeps the VALU dependency chain short —
// dot4 variants measured 18-22% slower on the latency-bound serial step.)
// ---------------------------------------------------------------------------
__global__ __launch_bounds__(512) void lstm_kernel(
    const float* __restrict__ Whh_f, const float* __restrict__ Whh_b,
    const float* __restrict__ pre,   // [2][512 r][512 t]
    bf16_t* __restrict__ h_all)      // [512][256]  (0:125 fwd | 125:250 bwd | 250:256 zero)
{
  const int dir = blockIdx.x;
  const float* __restrict__ Whh = dir ? Whh_b : Whh_f;

  const int tid  = threadIdx.x;
  const int lane = tid & 63;
  const int w    = tid >> 6;      // wave 0..7
  const int q    = lane >> 4;     // 0..3
  const int cc   = lane & 15;
  const int lt   = cc >> 2;       // local tile 0..3
  const int p    = cc & 3;        // gate index

  // ---- pass 1: global max |Whh| over used elements ----
  float wm = 0.0f;
  #pragma unroll
  for (int LT = 0; LT < 4; ++LT) {
    int rr = 16 * (4 * w + LT) + cc;
    int nn = rr >> 2, pp = rr & 3;
    if (nn < 125) {
      const float* __restrict__ Wrow = Whh + (125 * pp + nn) * 125;
      #pragma unroll
      for (int ks = 0; ks < 2; ++ks)
        #pragma unroll
        for (int jj = 0; jj < 16; ++jj) {
          int k = 64 * ks + 16 * q + jj;
          if (k < 125) wm = fmaxf(wm, fabsf(Wrow[k]));
        }
    }
  }
  #pragma unroll
  for (int off = 1; off < 64; off <<= 1)
    wm = fmaxf(wm, __shfl_xor(wm, off));
  __shared__ float wmx[8];
  if (lane == 0) wmx[w] = wm;
  __syncthreads();
  float wmax = wmx[0];
  #pragma unroll
  for (int u = 1; u < 8; ++u) wmax = fmaxf(wmax, wmx[u]);
  const float s_w  = 127.0f / wmax;
  const float invq = wmax / (127.0f * 127.0f);   // D -> W@h

  // ---- pass 2: quantize A fragments (i8, k = 64ks + 16q + jj) ----
  int4v afrag[4][2];
  #pragma unroll
  for (int LT = 0; LT < 4; ++LT) {
    int rr = 16 * (4 * w + LT) + cc;
    int nn = rr >> 2, pp = rr & 3;
    bool avld = (nn < 125);
    const float* __restrict__ Wrow = Whh + (avld ? (125 * pp + nn) * 125 : 0);
    #pragma unroll
    for (int ks = 0; ks < 2; ++ks) {
      int4v v;
      #pragma unroll
      for (int word = 0; word < 4; ++word) {
        int b = 0;
        #pragma unroll
        for (int byte = 0; byte < 4; ++byte) {
          int jj = 4 * word + byte;
          int k  = 64 * ks + 16 * q + jj;
          int qv = 0;
          if (avld && k < 125)
            qv = (int)__builtin_rintf(Wrow[k] * s_w);
          b |= (qv & 0xFF) << (8 * byte);
        }
        v[word] = b;
      }
      afrag[LT][ks] = v;
    }
  }

  __shared__ __align__(16) char hbuf[2][128];    // int8 h, double buffered
  if (tid < 256) hbuf[tid >> 7][tid & 127] = 0;
  // zero h_all pad columns once (dir 0 only)
  if (dir == 0) {
    #pragma unroll
    for (int u = 0; u < 6; ++u) h_all[tid * 256 + 250 + u] = (bf16_t)0.0f;
  }
  __syncthreads();

  const int   r_lane = 64 * w + 16 * lt + 4 * q + p;
  const int   nset   = 16 * w + 4 * lt + q;
  const float mult   = (p == 2) ? (-2.0f * LOG2E) : (-LOG2E);
  const float sA     = (p == 2) ? 2.0f : 1.0f;
  const float sB     = (p == 2) ? -1.0f : 0.0f;
  const float dscale = mult * invq;              // int D -> exp2 argument
  const float* __restrict__ preR = pre + dir * 262144 + r_lane * 512;
  float c = 0.0f;

  float4 pv_cur = *(const float4*)preR;

  for (int g = 0; g < 128; ++g) {
    float4 pv_nxt = make_float4(0.f, 0.f, 0.f, 0.f);
    if (g < 127) pv_nxt = *(const float4*)(preR + 4 * (g + 1));

    #pragma unroll
    for (int s4 = 0; s4 < 4; ++s4) {
      const int step = 4 * g + s4;
      const int cur  = s4 & 1, nxt = cur ^ 1;
      const float pv = (s4 == 0) ? pv_cur.x : (s4 == 1) ? pv_cur.y
                     : (s4 == 2) ? pv_cur.z : pv_cur.w;
      const float pvm = mult * pv;               // off critical path

      int4v b0 = *(const int4v*)&hbuf[cur][16 * q];
      int4v b1 = *(const int4v*)&hbuf[cur][64 + 16 * q];

      int4v acc[4];
      #pragma unroll
      for (int LT = 0; LT < 4; ++LT) {
        int4v a = (int4v)0;
        a = __builtin_amdgcn_mfma_i32_16x16x64_i8(afrag[LT][0], b0, a, 0, 0, 0);
        a = __builtin_amdgcn_mfma_i32_16x16x64_i8(afrag[LT][1], b1, a, 0, 0, 0);
        acc[LT] = a;
      }

      // select D for (lt, p) from own registers
      int gl[4];
      #pragma unroll
      for (int LT = 0; LT < 4; ++LT) {
        int a01 = (p & 1) ? acc[LT][1] : acc[LT][0];
        int a23 = (p & 1) ? acc[LT][3] : acc[LT][2];
        gl[LT] = (p & 2) ? a23 : a01;
      }
      int b01 = (lt & 1) ? gl[1] : gl[0];
      int b23 = (lt & 1) ? gl[3] : gl[2];
      int gsel = (lt & 2) ? b23 : b01;

      // uniform activation: y = sigmoid(scale*(W@h + pv)); act = sA*y + sB
      float gf  = (float)gsel;
      float xg  = fmaf(gf, dscale, pvm);
      float e   = __builtin_amdgcn_exp2f(xg);
      float y   = __builtin_amdgcn_rcpf(1.0f + e);
      float act = fmaf(y, sA, sB);

      // quad: p0=i, p1=f, p2=g~, p3=o  (flat broadcast tree)
      float b_i = qperm<0x00>(act);
      float b_f = qperm<0x55>(act);
      float b_g = qperm<0xAA>(act);
      float b_o = qperm<0xFF>(act);
      c = fmaf(b_f, c, b_i * b_g);               // c = f*c + i*g~
      float e2 = __builtin_amdgcn_exp2f(-2.0f * LOG2E * c);
      float tc = fmaf(__builtin_amdgcn_rcpf(1.0f + e2), 2.0f, -1.0f);
      float h  = b_o * tc;

      if (p == 0) {
        int qh = (int)__builtin_rintf(h * 127.0f);
        hbuf[nxt][nset] = (char)qh;              // pad units stay exactly 0
        if (nset < 125) {
          int t_orig = dir ? (511 - step) : step;
          h_all[t_orig * 256 + dir * 125 + nset] = (bf16_t)h;
        }
      }
      lds_barrier();
    }
    pv_cur = pv_nxt;
  }
}

// ---------------------------------------------------------------------------
// K3: Ea[j][m] = exp2(C2 * (h @ W1[:, :250].T)[j][m])
//     Eb[j][m] = exp2(C2 * ((h @ W1[:, 250:].T)[j][m] + b1[m]))
// C2 = 2*log2(e).  Storing the EXPONENTIALS (not the linear values) halves
// K4's transcendental count: exp2(sa+sb) = Ea*Eb, so the 134M-element outer
// loop needs only a v_mul instead of v_exp_f32 (exp2 count drops 134M->524K).
// bf16 MFMA, one 16x16 tile/wave.
// ---------------------------------------------------------------------------
__global__ __launch_bounds__(256) void qgemm_kernel(
    const bf16_t* __restrict__ h_all, // [512][256]
    const float* __restrict__ W1,     // [512][500]
    const float* __restrict__ b1,     // [512]
    float* __restrict__ Ea,           // [512][512]
    float* __restrict__ Eb)           // [512][512]
{
  const int tid  = threadIdx.x;
  const int wv   = tid >> 6;
  const int lane = tid & 63;
  const int q    = lane >> 4, cc = lane & 15;
  const int bj   = blockIdx.x & 31;    // j tile
  const int bm   = blockIdx.x >> 5;    // m group
  const int m    = bm * 64 + wv * 16 + cc;   // [0,1024)
  const int j0   = bj * 16;
  const int jA   = j0 + cc;

  const bool isB = (m >= 512);
  const int  row = isB ? (m - 512) : m;
  const int  cof = isB ? 250 : 0;

  f32x4 acc = (f32x4)0.0f;
  #pragma unroll
  for (int ks = 0; ks < 8; ++ks) {
    int kb = 32 * ks + 8 * q;
    bf16x8 a = *(const bf16x8*)&h_all[jA * 256 + kb];
    bf16x8 b;
    #pragma unroll
    for (int jj = 0; jj < 8; ++jj) {
      int k = kb + jj;
      float v = (k < 250) ? W1[row * 500 + cof + k] : 0.0f;
      b[jj] = (bf16_t)v;
    }
    acc = __builtin_amdgcn_mfma_f32_16x16x32_bf16(a, b, acc, 0, 0, 0);
  }

  const float C2 = 2.0f * LOG2E;
  #pragma unroll
  for (int reg = 0; reg < 4; ++reg) {
    int j = j0 + 4 * q + reg;
    float v = acc[reg];
    if (!isB) Ea[j * 512 + m] = __builtin_amdgcn_exp2f(C2 * v);
    else      Eb[j * 512 + (m - 512)] =
                  __builtin_amdgcn_exp2f(C2 * (v + b1[m - 512]));
  }
}

// ---------------------------------------------------------------------------
// K4: out[i][j] = b2 + sum_k W2[k] * tanh(Pa[j,k]+Pb[i,k]+b1[k])
//     tanh = 1 - 2*rcp(1 + Ea[j,k]*Eb[i,k])   (exp2's precomputed in K3)
//     accumulate accR = sum w*r;  out = wsum - 2*accR + b2
// Limits stay correct: Ea*Eb -> inf => r=0 => tanh=1; -> 0 => tanh=-1.
// ---------------------------------------------------------------------------
__global__ __launch_bounds__(256) void outer_kernel(
    const float* __restrict__ Ea, const float* __restrict__ Eb,
    const float* __restrict__ W2, const float* __restrict__ b2,
    float* __restrict__ out)
{
  __shared__ float sa[2][32][33];
  __shared__ float sb[2][32][33];
  __shared__ float sw[2][32];

  const int tid = threadIdx.x;
  const int bi  = blockIdx.x >> 4, bjx = blockIdx.x & 15;
  const int i0  = bi * 32, j0 = bjx * 32;
  const int ii0 = (tid & 15) * 2;
  const int jj0 = (tid >> 4) * 2;
  const int ljj = tid & 31, kk4 = (tid >> 5) * 4;

  float accR[2][2] = {{0.0f, 0.0f}, {0.0f, 0.0f}};
  float wsum = 0.0f;

  for (int kc = 0; kc < 16; ++kc) {
    const int buf = kc & 1;
    const int k0  = kc * 32;
    float4 va = *(const float4*)&Ea[(j0 + ljj) * 512 + k0 + kk4];
    float4 vb = *(const float4*)&Eb[(i0 + ljj) * 512 + k0 + kk4];
    sa[buf][kk4 + 0][ljj] = va.x; sa[buf][kk4 + 1][ljj] = va.y;
    sa[buf][kk4 + 2][ljj] = va.z; sa[buf][kk4 + 3][ljj] = va.w;
    sb[buf][kk4 + 0][ljj] = vb.x; sb[buf][kk4 + 1][ljj] = vb.y;
    sb[buf][kk4 + 2][ljj] = vb.z; sb[buf][kk4 + 3][ljj] = vb.w;
    if (tid < 32) sw[buf][tid] = W2[k0 + tid];
    __syncthreads();

    #pragma unroll 4
    for (int kk = 0; kk < 32; ++kk) {
      float2 av = *(const float2*)&sa[buf][kk][jj0];
      float2 bv = *(const float2*)&sb[buf][kk][ii0];
      float wk = sw[buf][kk];
      wsum += wk;
      {
        float e = av.x * bv.x;
        accR[0][0] = fmaf(wk, __builtin_amdgcn_rcpf(1.0f + e), accR[0][0]);
      }
      {
        float e = av.y * bv.x;
        accR[0][1] = fmaf(wk, __builtin_amdgcn_rcpf(1.0f + e), accR[0][1]);
      }
      {
        float e = av.x * bv.y;
        accR[1][0] = fmaf(wk, __builtin_amdgcn_rcpf(1.0f + e), accR[1][0]);
      }
      {
        float e = av.y * bv.y;
        accR[1][1] = fmaf(wk, __builtin_amdgcn_rcpf(1.0f + e), accR[1][1]);
      }
    }
  }

  const float bb = b2[0];
  #pragma unroll
  for (int i2 = 0; i2 < 2; ++i2)
    #pragma unroll
    for (int j2 = 0; j2 < 2; ++j2)
      out[(i0 + ii0 + i2) * 512 + (j0 + jj0 + j2)] =
          wsum - 2.0f * accR[i2][j2] + bb;
}

// ---------------------------------------------------------------------------
extern "C" void kernel_launch(void* const* d_in, const int* in_sizes, int n_in,
                              void* d_out, int out_size, void* d_ws, size_t ws_size,
                              hipStream_t stream) {
  const float* emb   = (const float*)d_in[0];
  const float* Wih_f = (const float*)d_in[1];
  const float* Whh_f = (const float*)d_in[2];
  const float* bih_f = (const float*)d_in[3];
  const float* bhh_f = (const float*)d_in[4];
  const float* Wih_b = (const float*)d_in[5];
  const float* Whh_b = (const float*)d_in[6];
  const float* bih_b = (const float*)d_in[7];
  const float* bhh_b = (const float*)d_in[8];
  const float* W1    = (const float*)d_in[9];
  const float* b1    = (const float*)d_in[10];
  const float* W2    = (const float*)d_in[11];
  const float* b2    = (const float*)d_in[12];
  float* out = (float*)d_out;

  char* ws = (char*)d_ws;
  float*  pre   = (float*)ws;                                  // 2 MB
  bf16_t* h_all = (bf16_t*)(ws + 2 * 1024 * 1024);             // 256 KB
  float*  Ea    = (float*)(ws + 2 * 1024 * 1024 + 256 * 1024); // 1 MB
  float*  Eb    = Ea + 512 * 512;                              // 1 MB

  pre_kernel<<<64, 256, 0, stream>>>(emb, Wih_f, bih_f, bhh_f,
                                     Wih_b, bih_b, bhh_b, pre);
  lstm_kernel<<<2, 512, 0, stream>>>(Whh_f, Whh_b, pre, h_all);
  qgemm_kernel<<<512, 256, 0, stream>>>(h_all, W1, b1, Ea, Eb);
  outer_kernel<<<256, 256, 0, stream>>>(Ea, Eb, W2, b2, out);
}

// Round 4
// 318.933 us; speedup vs baseline: 1.1874x; 1.0183x over previous
//
#include <hip/hip_runtime.h>

typedef __bf16 bf16_t;
typedef __bf16 bf16x8 __attribute__((ext_vector_type(8)));
typedef float f32x4 __attribute__((ext_vector_type(4)));
typedef int   int4v __attribute__((ext_vector_type(4)));

#define LOG2E 1.4426950408889634f

template<int CTRL>
__device__ __forceinline__ float qperm(float x) {
  return __builtin_bit_cast(float,
      __builtin_amdgcn_update_dpp(0, __builtin_bit_cast(int, x), CTRL, 0xF, 0xF, true));
}

// LDS-only barrier: does NOT drain vmcnt, so global loads/stores stay in
// flight across steps (compiler's __syncthreads drains vmcnt(0) every step).
__device__ __forceinline__ void lds_barrier() {
  asm volatile("s_waitcnt lgkmcnt(0)\n\ts_barrier" ::: "memory");
}

// ---------------------------------------------------------------------------
// K1: preT[dir][r][t] = (Wih_dir @ x[t_x]) + bih + bhh, gate-interleaved rows:
//     r = 4n + p  <->  original row j = 125*p + n   (n<125 valid, else 0)
//     t_x = t (fwd) or 511-t (bwd).
// MFMA GEMM with bf16 hi/lo split (Whi*xhi + Whi*xlo + Wlo*xhi): fp32-exact
// to ~2^-18.  grid = 64 blocks (dir*32 + row-tile T), 256 threads (4 waves),
// each wave does 8 t-tiles of 16.
// ---------------------------------------------------------------------------
__global__ __launch_bounds__(256) void pre_kernel(
    const float* __restrict__ x,     // [512][125]
    const float* __restrict__ Wih_f, const float* __restrict__ bih_f,
    const float* __restrict__ bhh_f,
    const float* __restrict__ Wih_b, const float* __restrict__ bih_b,
    const float* __restrict__ bhh_b,
    float* __restrict__ preT)        // [2][512 r][512 t]
{
  const int dir = blockIdx.x >> 5;
  const int T   = blockIdx.x & 31;
  const float* __restrict__ Wih = dir ? Wih_b : Wih_f;
  const float* __restrict__ bih = dir ? bih_b : bih_f;
  const float* __restrict__ bhh = dir ? bhh_b : bhh_f;

  const int tid = threadIdx.x;
  const int wv  = tid >> 6;
  const int lane = tid & 63;
  const int q = lane >> 4, cc = lane & 15;

  // A fragments for row-tile T: row r = 16T + cc, k = 32ks + 8q + j
  const int r  = 16 * T + cc;
  const int na = r >> 2, pa = r & 3;
  const bool vld = (na < 125);
  const float* __restrict__ Wr = Wih + (vld ? (125 * pa + na) * 125 : 0);

  bf16x8 whi[4], wlo[4];
  #pragma unroll
  for (int ks = 0; ks < 4; ++ks) {
    #pragma unroll
    for (int j = 0; j < 8; ++j) {
      int k = 32 * ks + 8 * q + j;
      float wvv = (vld && k < 125) ? Wr[k] : 0.0f;
      bf16_t hi = (bf16_t)wvv;
      whi[ks][j] = hi;
      wlo[ks][j] = (bf16_t)(wvv - (float)hi);
    }
  }

  // bias for the 4 output rows this lane stores
  float bias[4];
  #pragma unroll
  for (int reg = 0; reg < 4; ++reg) {
    int ro = 16 * T + 4 * q + reg;
    int no = ro >> 2, po = ro & 3;
    bias[reg] = (no < 125) ? (bih[125 * po + no] + bhh[125 * po + no]) : 0.0f;
  }

  for (int i = 0; i < 8; ++i) {
    const int tt = 8 * wv + i;
    const int t  = 16 * tt + cc;
    const int trow = dir ? (511 - t) : t;
    const float* __restrict__ xr = x + trow * 125;

    f32x4 acc = (f32x4)0.0f;
    #pragma unroll
    for (int ks = 0; ks < 4; ++ks) {
      bf16x8 xhi, xlo;
      #pragma unroll
      for (int j = 0; j < 8; ++j) {
        int k = 32 * ks + 8 * q + j;
        float xv = (k < 125) ? xr[k] : 0.0f;
        bf16_t hi = (bf16_t)xv;
        xhi[j] = hi;
        xlo[j] = (bf16_t)(xv - (float)hi);
      }
      acc = __builtin_amdgcn_mfma_f32_16x16x32_bf16(whi[ks], xhi, acc, 0, 0, 0);
      acc = __builtin_amdgcn_mfma_f32_16x16x32_bf16(whi[ks], xlo, acc, 0, 0, 0);
      acc = __builtin_amdgcn_mfma_f32_16x16x32_bf16(wlo[ks], xhi, acc, 0, 0, 0);
    }
    #pragma unroll
    for (int reg = 0; reg < 4; ++reg) {
      int ro = 16 * T + 4 * q + reg;
      preT[dir * 262144 + ro * 512 + 16 * tt + cc] = acc[reg] + bias[reg];
    }
  }
}

// ---------------------------------------------------------------------------
// K2: sequential LSTM.  grid = 2 blocks (dir), 512 threads (8 waves).
// Whh@h via mfma_i32_16x16x64_i8 (int8 quantized: h scale 127 exact since
// |h|<1; W global scale 127/max|W| computed on-device).  int32 accumulate is
// exact; dequant folded into the exp2 multiplier.
// Lane 16q + 4lt + p owns gate p of unit n = 16w + 4lt + q.
// (Round-0 proven structure: MFMA keeps the VALU dependency chain short —
// dot4 variants measured 18-22% slower on the latency-bound serial step.)
// ---------------------------------------------------------------------------
__global__ __launch_bounds__(512) void lstm_kernel(
    const float* __restrict__ Whh_f, const float* __restrict__ Whh_b,
    const float* __restrict__ pre,   // [2][512 r][512 t]
    bf16_t* __restrict__ h_all)      // [512][256]  (0:125 fwd | 125:250 bwd | 250:256 zero)
{
  const int dir = blockIdx.x;
  const float* __restrict__ Whh = dir ? Whh_b : Whh_f;

  const int tid  = threadIdx.x;
  const int lane = tid & 63;
  const int w    = tid >> 6;      // wave 0..7
  const int q    = lane >> 4;     // 0..3
  const int cc   = lane & 15;
  const int lt   = cc >> 2;       // local tile 0..3
  const int p    = cc & 3;        // gate index

  // ---- pass 1: global max |Whh| over used elements ----
  float wm = 0.0f;
  #pragma unroll
  for (int LT = 0; LT < 4; ++LT) {
    int rr = 16 * (4 * w + LT) + cc;
    int nn = rr >> 2, pp = rr & 3;
    if (nn < 125) {
      const float* __restrict__ Wrow = Whh + (125 * pp + nn) * 125;
      #pragma unroll
      for (int ks = 0; ks < 2; ++ks)
        #pragma unroll
        for (int jj = 0; jj < 16; ++jj) {
          int k = 64 * ks + 16 * q + jj;
          if (k < 125) wm = fmaxf(wm, fabsf(Wrow[k]));
        }
    }
  }
  #pragma unroll
  for (int off = 1; off < 64; off <<= 1)
    wm = fmaxf(wm, __shfl_xor(wm, off));
  __shared__ float wmx[8];
  if (lane == 0) wmx[w] = wm;
  __syncthreads();
  float wmax = wmx[0];
  #pragma unroll
  for (int u = 1; u < 8; ++u) wmax = fmaxf(wmax, wmx[u]);
  const float s_w  = 127.0f / wmax;
  const float invq = wmax / (127.0f * 127.0f);   // D -> W@h

  // ---- pass 2: quantize A fragments (i8, k = 64ks + 16q + jj) ----
  int4v afrag[4][2];
  #pragma unroll
  for (int LT = 0; LT < 4; ++LT) {
    int rr = 16 * (4 * w + LT) + cc;
    int nn = rr >> 2, pp = rr & 3;
    bool avld = (nn < 125);
    const float* __restrict__ Wrow = Whh + (avld ? (125 * pp + nn) * 125 : 0);
    #pragma unroll
    for (int ks = 0; ks < 2; ++ks) {
      int4v v;
      #pragma unroll
      for (int word = 0; word < 4; ++word) {
        int b = 0;
        #pragma unroll
        for (int byte = 0; byte < 4; ++byte) {
          int jj = 4 * word + byte;
          int k  = 64 * ks + 16 * q + jj;
          int qv = 0;
          if (avld && k < 125)
            qv = (int)__builtin_rintf(Wrow[k] * s_w);
          b |= (qv & 0xFF) << (8 * byte);
        }
        v[word] = b;
      }
      afrag[LT][ks] = v;
    }
  }

  __shared__ __align__(16) char hbuf[2][128];    // int8 h, double buffered
  if (tid < 256) hbuf[tid >> 7][tid & 127] = 0;
  // zero h_all pad columns once (dir 0 only)
  if (dir == 0) {
    #pragma unroll
    for (int u = 0; u < 6; ++u) h_all[tid * 256 + 250 + u] = (bf16_t)0.0f;
  }
  __syncthreads();

  const int   r_lane = 64 * w + 16 * lt + 4 * q + p;
  const int   nset   = 16 * w + 4 * lt + q;
  const float mult   = (p == 2) ? (-2.0f * LOG2E) : (-LOG2E);
  const float sA     = (p == 2) ? 2.0f : 1.0f;
  const float sB     = (p == 2) ? -1.0f : 0.0f;
  const float dscale = mult * invq;              // int D -> exp2 argument
  const float* __restrict__ preR = pre + dir * 262144 + r_lane * 512;
  float c = 0.0f;

  float4 pv_cur = *(const float4*)preR;

  for (int g = 0; g < 128; ++g) {
    float4 pv_nxt = make_float4(0.f, 0.f, 0.f, 0.f);
    if (g < 127) pv_nxt = *(const float4*)(preR + 4 * (g + 1));

    #pragma unroll
    for (int s4 = 0; s4 < 4; ++s4) {
      const int step = 4 * g + s4;
      const int cur  = s4 & 1, nxt = cur ^ 1;
      const float pv = (s4 == 0) ? pv_cur.x : (s4 == 1) ? pv_cur.y
                     : (s4 == 2) ? pv_cur.z : pv_cur.w;
      const float pvm = mult * pv;               // off critical path

      int4v b0 = *(const int4v*)&hbuf[cur][16 * q];
      int4v b1 = *(const int4v*)&hbuf[cur][64 + 16 * q];

      int4v acc[4];
      #pragma unroll
      for (int LT = 0; LT < 4; ++LT) {
        int4v a = (int4v)0;
        a = __builtin_amdgcn_mfma_i32_16x16x64_i8(afrag[LT][0], b0, a, 0, 0, 0);
        a = __builtin_amdgcn_mfma_i32_16x16x64_i8(afrag[LT][1], b1, a, 0, 0, 0);
        acc[LT] = a;
      }

      // select D for (lt, p) from own registers
      int gl[4];
      #pragma unroll
      for (int LT = 0; LT < 4; ++LT) {
        int a01 = (p & 1) ? acc[LT][1] : acc[LT][0];
        int a23 = (p & 1) ? acc[LT][3] : acc[LT][2];
        gl[LT] = (p & 2) ? a23 : a01;
      }
      int b01 = (lt & 1) ? gl[1] : gl[0];
      int b23 = (lt & 1) ? gl[3] : gl[2];
      int gsel = (lt & 2) ? b23 : b01;

      // uniform activation: y = sigmoid(scale*(W@h + pv)); act = sA*y + sB
      float gf  = (float)gsel;
      float xg  = fmaf(gf, dscale, pvm);
      float e   = __builtin_amdgcn_exp2f(xg);
      float y   = __builtin_amdgcn_rcpf(1.0f + e);
      float act = fmaf(y, sA, sB);

      // quad: p0=i, p1=f, p2=g~, p3=o  (flat broadcast tree)
      float b_i = qperm<0x00>(act);
      float b_f = qperm<0x55>(act);
      float b_g = qperm<0xAA>(act);
      float b_o = qperm<0xFF>(act);
      c = fmaf(b_f, c, b_i * b_g);               // c = f*c + i*g~
      float e2 = __builtin_amdgcn_exp2f(-2.0f * LOG2E * c);
      float tc = fmaf(__builtin_amdgcn_rcpf(1.0f + e2), 2.0f, -1.0f);
      float h  = b_o * tc;

      if (p == 0) {
        int qh = (int)__builtin_rintf(h * 127.0f);
        hbuf[nxt][nset] = (char)qh;              // pad units stay exactly 0
        if (nset < 125) {
          int t_orig = dir ? (511 - step) : step;
          h_all[t_orig * 256 + dir * 125 + nset] = (bf16_t)h;
        }
      }
      lds_barrier();
    }
    pv_cur = pv_nxt;
  }
}

// ---------------------------------------------------------------------------
// K3: Ea[j][m] = exp2(C2 * (h @ W1[:, :250].T)[j][m])
//     Eb[j][m] = exp2(C2 * ((h @ W1[:, 250:].T)[j][m] + b1[m]))
// C2 = 2*log2(e).  Storing the EXPONENTIALS (not the linear values) halves
// K4's transcendental count: exp2(sa+sb) = Ea*Eb, so the 134M-element outer
// loop needs only a v_mul instead of v_exp_f32 (exp2 count drops 134M->524K).
// bf16 MFMA, one 16x16 tile/wave.
// ---------------------------------------------------------------------------
__global__ __launch_bounds__(256) void qgemm_kernel(
    const bf16_t* __restrict__ h_all, // [512][256]
    const float* __restrict__ W1,     // [512][500]
    const float* __restrict__ b1,     // [512]
    float* __restrict__ Ea,           // [512][512]
    float* __restrict__ Eb)           // [512][512]
{
  const int tid  = threadIdx.x;
  const int wv   = tid >> 6;
  const int lane = tid & 63;
  const int q    = lane >> 4, cc = lane & 15;
  const int bj   = blockIdx.x & 31;    // j tile
  const int bm   = blockIdx.x >> 5;    // m group
  const int m    = bm * 64 + wv * 16 + cc;   // [0,1024)
  const int j0   = bj * 16;
  const int jA   = j0 + cc;

  const bool isB = (m >= 512);
  const int  row = isB ? (m - 512) : m;
  const int  cof = isB ? 250 : 0;

  f32x4 acc = (f32x4)0.0f;
  #pragma unroll
  for (int ks = 0; ks < 8; ++ks) {
    int kb = 32 * ks + 8 * q;
    bf16x8 a = *(const bf16x8*)&h_all[jA * 256 + kb];
    bf16x8 b;
    #pragma unroll
    for (int jj = 0; jj < 8; ++jj) {
      int k = kb + jj;
      float v = (k < 250) ? W1[row * 500 + cof + k] : 0.0f;
      b[jj] = (bf16_t)v;
    }
    acc = __builtin_amdgcn_mfma_f32_16x16x32_bf16(a, b, acc, 0, 0, 0);
  }

  const float C2 = 2.0f * LOG2E;
  #pragma unroll
  for (int reg = 0; reg < 4; ++reg) {
    int j = j0 + 4 * q + reg;
    float v = acc[reg];
    if (!isB) Ea[j * 512 + m] = __builtin_amdgcn_exp2f(C2 * v);
    else      Eb[j * 512 + (m - 512)] =
                  __builtin_amdgcn_exp2f(C2 * (v + b1[m - 512]));
  }
}

// ---------------------------------------------------------------------------
// K4: out[i][j] = b2 + sum_k W2[k] * tanh(Pa[j,k]+Pb[i,k]+b1[k])
//     tanh = 1 - 2*rcp(1 + Ea[j,k]*Eb[i,k])   (exp2's precomputed in K3)
//     accumulate accR = sum w*r;  out = wsum - 2*accR + b2
// k-PAIRED: w1/(1+e1) + w2/(1+e2) = [w1(1+e2)+w2(1+e1)] / [(1+e1)(1+e2)]
//   -> ONE rcp per 2 k (halves trans-pipe issue).  Exact algebra; overflow-
//   safe (e <= 2^58 so den <= 2^116, num finite; no inf/NaN path).
// 512 blocks (2/CU -> 2 waves/SIMD hides rcp->fma latency), 16i x 32j tile,
// 2 outputs/thread.  LDS k-minor (pad 36) so each pair is one float2 read.
// ---------------------------------------------------------------------------
__global__ __launch_bounds__(256) void outer_kernel(
    const float* __restrict__ Ea, const float* __restrict__ Eb,
    const float* __restrict__ W2, const float* __restrict__ b2,
    float* __restrict__ out)
{
  __shared__ float sa2[2][32][36];   // [buf][j][k]
  __shared__ float sb2[2][16][36];   // [buf][i][k]
  __shared__ float sw[2][32];

  const int tid = threadIdx.x;
  const int bi  = blockIdx.x >> 4;       // 0..31 -> i tile of 16
  const int bjx = blockIdx.x & 15;       // 0..15 -> j tile of 32
  const int i0  = bi * 16, j0 = bjx * 32;
  const int ii  = tid & 15;              // output i
  const int jj2 = tid >> 4;              // output j pair: j0 + 2*jj2 + {0,1}

  const int lj  = tid & 31, lk4 = (tid >> 5) * 4;   // sa2 loader coords
  const int li  = tid & 15, lk4b = ((tid >> 4) & 7) * 4; // sb2 loader coords

  float accR0 = 0.0f, accR1 = 0.0f;
  float wsum = 0.0f;

  for (int kc = 0; kc < 16; ++kc) {
    const int buf = kc & 1;
    const int k0  = kc * 32;
    float4 va = *(const float4*)&Ea[(j0 + lj) * 512 + k0 + lk4];
    *(float4*)&sa2[buf][lj][lk4] = va;
    if (tid < 128) {
      float4 vb = *(const float4*)&Eb[(i0 + li) * 512 + k0 + lk4b];
      *(float4*)&sb2[buf][li][lk4b] = vb;
    }
    if (tid < 32) sw[buf][tid] = W2[k0 + tid];
    __syncthreads();

    #pragma unroll 4
    for (int kk = 0; kk < 32; kk += 2) {
      float2 wv = *(const float2*)&sw[buf][kk];
      float2 bv = *(const float2*)&sb2[buf][ii][kk];
      float2 a0 = *(const float2*)&sa2[buf][2 * jj2 + 0][kk];
      float2 a1 = *(const float2*)&sa2[buf][2 * jj2 + 1][kk];
      wsum += wv.x + wv.y;
      {
        float t1  = fmaf(a0.x, bv.x, 1.0f);
        float t2  = fmaf(a0.y, bv.y, 1.0f);
        float den = t1 * t2;
        float num = fmaf(wv.x, t2, wv.y * t1);
        accR0 = fmaf(num, __builtin_amdgcn_rcpf(den), accR0);
      }
      {
        float t1  = fmaf(a1.x, bv.x, 1.0f);
        float t2  = fmaf(a1.y, bv.y, 1.0f);
        float den = t1 * t2;
        float num = fmaf(wv.x, t2, wv.y * t1);
        accR1 = fmaf(num, __builtin_amdgcn_rcpf(den), accR1);
      }
    }
  }

  const float bb = b2[0];
  float2 o;
  o.x = wsum - 2.0f * accR0 + bb;
  o.y = wsum - 2.0f * accR1 + bb;
  *(float2*)&out[(i0 + ii) * 512 + j0 + 2 * jj2] = o;
}

// ---------------------------------------------------------------------------
extern "C" void kernel_launch(void* const* d_in, const int* in_sizes, int n_in,
                              void* d_out, int out_size, void* d_ws, size_t ws_size,
                              hipStream_t stream) {
  const float* emb   = (const float*)d_in[0];
  const float* Wih_f = (const float*)d_in[1];
  const float* Whh_f = (const float*)d_in[2];
  const float* bih_f = (const float*)d_in[3];
  const float* bhh_f = (const float*)d_in[4];
  const float* Wih_b = (const float*)d_in[5];
  const float* Whh_b = (const float*)d_in[6];
  const float* bih_b = (const float*)d_in[7];
  const float* bhh_b = (const float*)d_in[8];
  const float* W1    = (const float*)d_in[9];
  const float* b1    = (const float*)d_in[10];
  const float* W2    = (const float*)d_in[11];
  const float* b2    = (const float*)d_in[12];
  float* out = (float*)d_out;

  char* ws = (char*)d_ws;
  float*  pre   = (float*)ws;                                  // 2 MB
  bf16_t* h_all = (bf16_t*)(ws + 2 * 1024 * 1024);             // 256 KB
  float*  Ea    = (float*)(ws + 2 * 1024 * 1024 + 256 * 1024); // 1 MB
  float*  Eb    = Ea + 512 * 512;                              // 1 MB

  pre_kernel<<<64, 256, 0, stream>>>(emb, Wih_f, bih_f, bhh_f,
                                     Wih_b, bih_b, bhh_b, pre);
  lstm_kernel<<<2, 512, 0, stream>>>(Whh_f, Whh_b, pre, h_all);
  qgemm_kernel<<<512, 256, 0, stream>>>(h_all, W1, b1, Ea, Eb);
  outer_kernel<<<512, 256, 0, stream>>>(Ea, Eb, W2, b2, out);
}